// Round 11
// baseline (62.073 us; speedup 1.0000x reference)
//
#include <hip/hip_runtime.h>
#include <hip/hip_fp16.h>

typedef unsigned int u32;
typedef __attribute__((ext_vector_type(4)))  u32 u32x4;
typedef __attribute__((ext_vector_type(16))) u32 u32x16;

// ---------------- packed-f16 tropical primitives ----------------
// half2 lanes carry (main path, shortcut path) through the whole pipeline.
static __device__ __forceinline__ u32 pk_add_sv(u32 s, u32 v) {
    u32 d; asm("v_pk_add_f16 %0, %1, %2" : "=v"(d) : "s"(s), "v"(v)); return d;
}
static __device__ __forceinline__ u32 pk_add_vv(u32 a, u32 b) {
    u32 d; asm("v_pk_add_f16 %0, %1, %2" : "=v"(d) : "v"(a), "v"(b)); return d;
}
static __device__ __forceinline__ u32 pk_min_vv(u32 a, u32 b) {
    u32 d; asm("v_pk_min_f16 %0, %1, %2" : "=v"(d) : "v"(a), "v"(b)); return d;
}
static __device__ __forceinline__ u32 pk_min_sv(u32 s, u32 v) {
    u32 d; asm("v_pk_min_f16 %0, %1, %2" : "=v"(d) : "s"(s), "v"(v)); return d;
}
static __device__ __forceinline__ u32 pk_max_vv(u32 a, u32 b) {
    u32 d; asm("v_pk_max_f16 %0, %1, %2" : "=v"(d) : "v"(a), "v"(b)); return d;
}
static __device__ __forceinline__ u32 packh2(float lo, float hi) {
    const unsigned short l = __half_as_ushort(__float2half_rn(lo));
    const unsigned short h = __half_as_ushort(__float2half_rn(hi));
    return (u32)l | ((u32)h << 16);
}
static __device__ __forceinline__ u32 duph(float v) {
    return (u32)__half_as_ushort(__float2half_rn(v)) * 0x10001u;
}
static __device__ __forceinline__ float h2lo(u32 v) {
    return __half2float(__ushort_as_half((unsigned short)(v & 0xffffu)));
}
static __device__ __forceinline__ float h2hi(u32 v) {
    return __half2float(__ushort_as_half((unsigned short)(v >> 16)));
}
// Force a wave-uniform pointer into SGPRs (s_load base must be scalar).
static __device__ __forceinline__ const u32* uniform_ptr(const u32* p) {
    const u32 lo = __builtin_amdgcn_readfirstlane((u32)(size_t)p);
    const u32 hi = __builtin_amdgcn_readfirstlane((u32)((size_t)p >> 32));
    return (const u32*)(((size_t)hi << 32) | (size_t)lo);
}

// ---------------- convert: pack weights + build dup'd-x table ----------------
// wpk1[(col>>6)*32768 + kq*256 + (col&63)*4 + e] = (W1[4kq+e][col], Wm[..])  512 KB
// wpk2[(col>>6)*16384 + iq*256 + (col&63)*4 + e] = (W2[4iq+e][col], Ws[..])  256 KB
// xdup[kq*4096 + row*4 + e] = dup_f16(x[row][4kq+e])                         2 MB
__global__ __launch_bounds__(256) void convert_pack(
    const float* __restrict__ W1, const float* __restrict__ Wm,
    const float* __restrict__ W2, const float* __restrict__ Ws,
    const float* __restrict__ x,
    u32* __restrict__ wpk1, u32* __restrict__ wpk2, u32* __restrict__ xdup)
{
    const int stride = gridDim.x * blockDim.x;
    const int t0 = blockIdx.x * blockDim.x + threadIdx.x;
    for (int t = t0; t < 512 * 256; t += stride) {
        const int k = t >> 8, col = t & 255;
        wpk1[(col >> 6) * 32768 + (k >> 2) * 256 + (col & 63) * 4 + (k & 3)]
            = packh2(W1[t], Wm[t]);
    }
    for (int t = t0; t < 256 * 256; t += stride) {
        const int i = t >> 8, col = t & 255;
        wpk2[(col >> 6) * 16384 + (i >> 2) * 256 + (col & 63) * 4 + (i & 3)]
            = packh2(W2[t], Ws[t]);
    }
    for (int t = t0; t < 128 * 1024; t += stride) {
        const int kq = t >> 10, row = t & 1023;
        const float4 f = *(const float4*)(x + (size_t)row * 512 + kq * 4);
        uint4 d;
        d.x = duph(f.x); d.y = duph(f.y); d.z = duph(f.z); d.w = duph(f.w);
        *(uint4*)(xdup + (size_t)kq * 4096 + row * 4) = d;   // coalesced 16B writes
    }
}

// ---------------- K1: h-partial = packed min-plus, k-split in two ----------------
// grid 512 = 4 js (64 cols) x 2 ksplit x 64 rowgroups (16 rows); 256 thr = 4 waves.
// Wave = 64 distinct cols x 4 wave-uniform rows -> x via s_load (SMEM pipe),
// weights via ONE ds_read_b128 per wave per k-quad. Depth-1 ping-pong, one
// lgkmcnt(0) per step. Inner loop: zero barriers, zero VMEM.
static __device__ __forceinline__ void k1_compute(
    const u32x4& w, const u32x16& x, u32 accA[4], u32 accB[4])
{
    #pragma unroll
    for (int r = 0; r < 4; ++r) {
        accA[r] = pk_min_vv(accA[r], pk_add_sv(x[4 * r + 0], w[0]));
        accB[r] = pk_min_vv(accB[r], pk_add_sv(x[4 * r + 1], w[1]));
        accA[r] = pk_min_vv(accA[r], pk_add_sv(x[4 * r + 2], w[2]));
        accB[r] = pk_min_vv(accB[r], pk_add_sv(x[4 * r + 3], w[3]));
    }
}

__global__ __launch_bounds__(256, 2) void k1_minplus(
    const u32* __restrict__ wpk1, const u32* __restrict__ xdup,
    u32* __restrict__ hpart)
{
    __shared__ __align__(16) u32 wl[16384];   // 64 KB: [64 kq][64 col][4 e]
    const int tid   = threadIdx.x;
    const int bid   = blockIdx.x;
    const int js    = bid & 3;          // bid&7 spans js x ks -> XCD round-robin
    const int ks    = (bid >> 2) & 1;
    const int rg    = bid >> 3;         // 0..63
    const int row0  = rg * 16;
    const int col64 = tid & 63;
    const int wv    = tid >> 6;         // wave 0..3, rows row0+wv*4 .. +3

    {   // stage the FULL 64 KB weight slice: 4096 uint4 = 256 thr x 16
        const uint4* src = (const uint4*)(wpk1 + js * 32768 + ks * 16384);
        uint4* dst = (uint4*)wl;
        #pragma unroll
        for (int s = 0; s < 16; ++s) dst[tid + s * 256] = src[tid + s * 256];
    }
    __syncthreads();                    // only barrier in the kernel

    const u32 lds0 = (u32)(size_t)&wl[0] + (u32)(col64 << 4);
    const u32* xb  = uniform_ptr(xdup + (size_t)ks * (64 * 4096)
                                 + (size_t)(row0 + wv * 4) * 4);

    u32x4  wb0, wb1;
    u32x16 xs0, xs1;

    asm volatile("ds_read_b128 %0, %1" : "=v"(wb0) : "v"(lds0));
    asm volatile("s_load_dwordx16 %0, %1, %2" : "=s"(xs0) : "s"(xb), "s"(0u));
    asm volatile("s_waitcnt lgkmcnt(0)" : "+v"(wb0), "+s"(xs0));
    __builtin_amdgcn_sched_barrier(0);

    u32 accA[4], accB[4];
    #pragma unroll
    for (int r = 0; r < 4; ++r) { accA[r] = 0x7C007C00u; accB[r] = 0x7C007C00u; }

    for (int kq = 0; kq < 62; kq += 2) {
        asm volatile("ds_read_b128 %0, %1" : "=v"(wb1) : "v"(lds0 + (u32)(kq + 1) * 1024u));
        asm volatile("s_load_dwordx16 %0, %1, %2" : "=s"(xs1) : "s"(xb), "s"((u32)((kq + 1) * 16384)));
        k1_compute(wb0, xs0, accA, accB);
        asm volatile("s_waitcnt lgkmcnt(0)" : "+v"(wb1), "+s"(xs1));
        __builtin_amdgcn_sched_barrier(0);
        asm volatile("ds_read_b128 %0, %1" : "=v"(wb0) : "v"(lds0 + (u32)(kq + 2) * 1024u));
        asm volatile("s_load_dwordx16 %0, %1, %2" : "=s"(xs0) : "s"(xb), "s"((u32)((kq + 2) * 16384)));
        k1_compute(wb1, xs1, accA, accB);
        asm volatile("s_waitcnt lgkmcnt(0)" : "+v"(wb0), "+s"(xs0));
        __builtin_amdgcn_sched_barrier(0);
    }
    // tail: kq=62 resident in buf0; issue 63, compute 62, wait, compute 63
    asm volatile("ds_read_b128 %0, %1" : "=v"(wb1) : "v"(lds0 + 63u * 1024u));
    asm volatile("s_load_dwordx16 %0, %1, %2" : "=s"(xs1) : "s"(xb), "s"((u32)(63 * 16384)));
    k1_compute(wb0, xs0, accA, accB);
    asm volatile("s_waitcnt lgkmcnt(0)" : "+v"(wb1), "+s"(xs1));
    __builtin_amdgcn_sched_barrier(0);
    k1_compute(wb1, xs1, accA, accB);

    u32* hp = hpart + (size_t)ks * 262144 + (size_t)(row0 + wv * 4) * 256
            + (js * 64 + col64);
    #pragma unroll
    for (int r = 0; r < 4; ++r) hp[(size_t)r * 256] = pk_min_vv(accA[r], accB[r]);
}

// ---------------- K2: out = min(max_i(h1+W2)+b2, max_i(hm+Ws)+bs) ----------------
// grid 512 = 4 js x 128 rowgroups (8 rows); 256 thr = 4 waves = 64 cols x 2 rows.
// h (both k-split partials) via s_load -> combined in-register with pk_min.
static __device__ __forceinline__ void k2_compute(
    const u32x4& w, const u32x4& hA0, const u32x4& hA1,
    const u32x4& hB0, const u32x4& hB1,
    u32& aA0, u32& aB0, u32& aA1, u32& aB1)
{
    #pragma unroll
    for (int e = 0; e < 4; ++e) {
        const u32 cA = pk_min_sv(hA1[e], hA0[e]);   // combine k-split partials
        const u32 cB = pk_min_sv(hB1[e], hB0[e]);
        if ((e & 1) == 0) {
            aA0 = pk_max_vv(aA0, pk_add_vv(cA, w[e]));
            aA1 = pk_max_vv(aA1, pk_add_vv(cB, w[e]));
        } else {
            aB0 = pk_max_vv(aB0, pk_add_vv(cA, w[e]));
            aB1 = pk_max_vv(aB1, pk_add_vv(cB, w[e]));
        }
    }
}

__global__ __launch_bounds__(256, 2) void k2_maxplus(
    const u32* __restrict__ wpk2, const u32* __restrict__ hpart,
    const float* __restrict__ b2, const float* __restrict__ bs,
    float* __restrict__ out)
{
    __shared__ __align__(16) u32 wl[16384];   // 64 KB: [64 iq][64 col][4 e]
    const int tid   = threadIdx.x;
    const int bid   = blockIdx.x;
    const int js    = bid & 3;
    const int rg    = bid >> 2;        // 0..127
    const int row0  = rg * 8;
    const int col64 = tid & 63;
    const int wv    = tid >> 6;
    const int col   = js * 64 + col64;
    const int rA    = row0 + wv * 2;
    const int rB    = rA + 1;

    {   // stage the FULL 64 KB weight slice: 4096 uint4 = 256 thr x 16
        const uint4* src = (const uint4*)(wpk2 + js * 16384);
        uint4* dst = (uint4*)wl;
        #pragma unroll
        for (int s = 0; s < 16; ++s) dst[tid + s * 256] = src[tid + s * 256];
    }
    __syncthreads();

    const u32 lds0 = (u32)(size_t)&wl[0] + (u32)(col64 << 4);
    const u32* hA0p = uniform_ptr(hpart + (size_t)rA * 256);
    const u32* hA1p = uniform_ptr(hpart + (size_t)rA * 256 + 262144);
    const u32* hB0p = uniform_ptr(hpart + (size_t)rB * 256);
    const u32* hB1p = uniform_ptr(hpart + (size_t)rB * 256 + 262144);

    u32x4 wb0, wb1, a0A, a0B, a0C, a0D, a1A, a1B, a1C, a1D;

    asm volatile("ds_read_b128 %0, %1" : "=v"(wb0) : "v"(lds0));
    asm volatile("s_load_dwordx4 %0, %1, %2" : "=s"(a0A) : "s"(hA0p), "s"(0u));
    asm volatile("s_load_dwordx4 %0, %1, %2" : "=s"(a0B) : "s"(hA1p), "s"(0u));
    asm volatile("s_load_dwordx4 %0, %1, %2" : "=s"(a0C) : "s"(hB0p), "s"(0u));
    asm volatile("s_load_dwordx4 %0, %1, %2" : "=s"(a0D) : "s"(hB1p), "s"(0u));
    asm volatile("s_waitcnt lgkmcnt(0)"
                 : "+v"(wb0), "+s"(a0A), "+s"(a0B), "+s"(a0C), "+s"(a0D));
    __builtin_amdgcn_sched_barrier(0);

    u32 aA0 = 0xFC00FC00u, aB0 = 0xFC00FC00u, aA1 = 0xFC00FC00u, aB1 = 0xFC00FC00u;

    for (int iq = 0; iq < 62; iq += 2) {
        const u32 o1 = (u32)((iq + 1) * 16);
        asm volatile("ds_read_b128 %0, %1" : "=v"(wb1) : "v"(lds0 + (u32)(iq + 1) * 1024u));
        asm volatile("s_load_dwordx4 %0, %1, %2" : "=s"(a1A) : "s"(hA0p), "s"(o1));
        asm volatile("s_load_dwordx4 %0, %1, %2" : "=s"(a1B) : "s"(hA1p), "s"(o1));
        asm volatile("s_load_dwordx4 %0, %1, %2" : "=s"(a1C) : "s"(hB0p), "s"(o1));
        asm volatile("s_load_dwordx4 %0, %1, %2" : "=s"(a1D) : "s"(hB1p), "s"(o1));
        k2_compute(wb0, a0A, a0B, a0C, a0D, aA0, aB0, aA1, aB1);
        asm volatile("s_waitcnt lgkmcnt(0)"
                     : "+v"(wb1), "+s"(a1A), "+s"(a1B), "+s"(a1C), "+s"(a1D));
        __builtin_amdgcn_sched_barrier(0);
        const u32 o2 = (u32)((iq + 2) * 16);
        asm volatile("ds_read_b128 %0, %1" : "=v"(wb0) : "v"(lds0 + (u32)(iq + 2) * 1024u));
        asm volatile("s_load_dwordx4 %0, %1, %2" : "=s"(a0A) : "s"(hA0p), "s"(o2));
        asm volatile("s_load_dwordx4 %0, %1, %2" : "=s"(a0B) : "s"(hA1p), "s"(o2));
        asm volatile("s_load_dwordx4 %0, %1, %2" : "=s"(a0C) : "s"(hB0p), "s"(o2));
        asm volatile("s_load_dwordx4 %0, %1, %2" : "=s"(a0D) : "s"(hB1p), "s"(o2));
        k2_compute(wb1, a1A, a1B, a1C, a1D, aA0, aB0, aA1, aB1);
        asm volatile("s_waitcnt lgkmcnt(0)"
                     : "+v"(wb0), "+s"(a0A), "+s"(a0B), "+s"(a0C), "+s"(a0D));
        __builtin_amdgcn_sched_barrier(0);
    }
    {   // tail: iq=62 in buf0; issue 63, compute 62, wait, compute 63
        const u32 o1 = (u32)(63 * 16);
        asm volatile("ds_read_b128 %0, %1" : "=v"(wb1) : "v"(lds0 + 63u * 1024u));
        asm volatile("s_load_dwordx4 %0, %1, %2" : "=s"(a1A) : "s"(hA0p), "s"(o1));
        asm volatile("s_load_dwordx4 %0, %1, %2" : "=s"(a1B) : "s"(hA1p), "s"(o1));
        asm volatile("s_load_dwordx4 %0, %1, %2" : "=s"(a1C) : "s"(hB0p), "s"(o1));
        asm volatile("s_load_dwordx4 %0, %1, %2" : "=s"(a1D) : "s"(hB1p), "s"(o1));
        k2_compute(wb0, a0A, a0B, a0C, a0D, aA0, aB0, aA1, aB1);
        asm volatile("s_waitcnt lgkmcnt(0)"
                     : "+v"(wb1), "+s"(a1A), "+s"(a1B), "+s"(a1C), "+s"(a1D));
        __builtin_amdgcn_sched_barrier(0);
        k2_compute(wb1, a1A, a1B, a1C, a1D, aA0, aB0, aA1, aB1);
    }

    const u32 mA = pk_max_vv(aA0, aB0);
    const u32 mB = pk_max_vv(aA1, aB1);
    const float bb2 = b2[col], bbs = bs[col];
    out[(size_t)rA * 256 + col] = fminf(h2lo(mA) + bb2, h2hi(mA) + bbs);
    out[(size_t)rB * 256 + col] = fminf(h2lo(mB) + bb2, h2hi(mB) + bbs);
}

extern "C" void kernel_launch(void* const* d_in, const int* in_sizes, int n_in,
                              void* d_out, int out_size, void* d_ws, size_t ws_size,
                              hipStream_t stream) {
    const float* x  = (const float*)d_in[0];
    const float* W1 = (const float*)d_in[1];
    const float* W2 = (const float*)d_in[2];
    const float* b2 = (const float*)d_in[3];
    const float* Wm = (const float*)d_in[4];
    const float* Ws = (const float*)d_in[5];
    const float* bs = (const float*)d_in[6];
    float* out = (float*)d_out;

    u32* wpk1  = (u32*)d_ws;             // 512 KB
    u32* wpk2  = wpk1 + 131072;          // 256 KB
    u32* xdup  = wpk2 + 65536;           // 2 MB
    u32* hpart = xdup + 524288;          // 2 x 1 MB (k-split partials)

    convert_pack<<<512, 256, 0, stream>>>(W1, Wm, W2, Ws, x, wpk1, wpk2, xdup);
    k1_minplus<<<512, 256, 0, stream>>>(wpk1, xdup, hpart);
    k2_maxplus<<<512, 256, 0, stream>>>(wpk2, hpart, b2, bs, out);
}